// Round 3
// baseline (778.835 us; speedup 1.0000x reference)
//
#include <hip/hip_runtime.h>
#include <hip/hip_bf16.h>

// CausalAttention: q=xWq,k=xWk,v=xWv; S=qk^T; causal mask (j>i -> -inf);
// softmax over AXIS=1 (query axis, i.e. COLUMN-wise over i) of S/32; out = W @ v.
// Strategy: P[i,j]=exp(s_ij/32) (no max-sub needed: |s/32|<~2.5), l_j=sum_{i>=j} P
// (fused into P-GEMM epilogue), fold 1/l_j into V rows -> out = P @ (V/l)^T.
// bf16 MFMA GEMMs, XOR-swizzled LDS (0 bank conflicts), XCD-aware block swizzle
// (consecutive-mod-8 ids share one XCD's L2 -> A-tile fetched once per XCD).

using bf16 = __hip_bfloat16;
typedef __attribute__((ext_vector_type(8))) short short8;
typedef __attribute__((ext_vector_type(4))) float f32x4;

__device__ __forceinline__ float bfbits2f(unsigned short u) {
  return __uint_as_float((unsigned)u << 16);
}

// ---------------- fp32 -> bf16 convert (x4 per thread) ----------------
__global__ void cvt_kernel(const float* __restrict__ in, bf16* __restrict__ out) {
  size_t i = ((size_t)blockIdx.x * 256 + threadIdx.x) * 4;
  float4 v = *(const float4*)(in + i);
  alignas(8) bf16 h[4] = {__float2bfloat16(v.x), __float2bfloat16(v.y),
                          __float2bfloat16(v.z), __float2bfloat16(v.w)};
  *(unsigned long long*)(out + i) = *(const unsigned long long*)h;
}

// ------- W[k][n] fp32 -> Wt[n][k] bf16 (64x64 LDS transpose, vectorized) -------
// z==3 slice: zero the 8*2048 column-sum buffer (folded launch).
__global__ void wt_kernel(const float* __restrict__ W0, const float* __restrict__ W1,
                          const float* __restrict__ W2, bf16* __restrict__ Wt,
                          float* __restrict__ lbuf) {
  int tid = threadIdx.x;
  if (blockIdx.z == 3) {
    int bid = blockIdx.y * 16 + blockIdx.x;
    if (bid < 64) lbuf[bid * 256 + tid] = 0.f;
    return;
  }
  const float* W = blockIdx.z == 0 ? W0 : blockIdx.z == 1 ? W1 : W2;
  bf16* O = Wt + (size_t)blockIdx.z * 1048576ull;
  __shared__ float t[64][65];
  int n0 = blockIdx.x * 64, k0 = blockIdx.y * 64;
#pragma unroll
  for (int i = 0; i < 4; ++i) {
    int idx = i * 1024 + tid * 4;
    int r = idx >> 6, c = idx & 63;
    float4 v = *(const float4*)(W + (size_t)(k0 + r) * 1024 + n0 + c);
    t[r][c] = v.x; t[r][c + 1] = v.y; t[r][c + 2] = v.z; t[r][c + 3] = v.w;
  }
  __syncthreads();
#pragma unroll
  for (int i = 0; i < 4; ++i) {
    int idx = i * 1024 + tid * 4;
    int r = idx >> 6, c = idx & 63;  // out row n0+r, k cols k0+c..c+3
    alignas(8) bf16 h[4] = {__float2bfloat16(t[c][r]), __float2bfloat16(t[c + 1][r]),
                            __float2bfloat16(t[c + 2][r]), __float2bfloat16(t[c + 3][r])};
    *(unsigned long long*)(O + (size_t)(n0 + r) * 1024 + k0 + c) = *(const unsigned long long*)h;
  }
}

// ------- Vt[e][j] = bf16( V[j][e] / l_j )  (64x64 LDS transpose, vectorized) -------
__global__ void vhat_kernel(const bf16* __restrict__ QKV, const float* __restrict__ l,
                            bf16* __restrict__ Vt) {
  int lb = blockIdx.z;
  const unsigned short* V =
      (const unsigned short*)QKV + ((size_t)lb * 3 + 2) * 2097152ull;  // V slot
  bf16* O = Vt + (size_t)lb * 2097152ull;
  const float* lc = l + lb * 2048;
  __shared__ float t[64][65];
  __shared__ float rl[64];
  int j0 = blockIdx.x * 64, e0 = blockIdx.y * 64;
  int tid = threadIdx.x;
  if (tid < 64) rl[tid] = 1.0f / lc[j0 + tid];
#pragma unroll
  for (int i = 0; i < 4; ++i) {
    int idx = i * 1024 + tid * 4;
    int r = idx >> 6, c = idx & 63;
    ushort4 u = *(const ushort4*)(V + (size_t)(j0 + r) * 1024 + e0 + c);
    t[r][c] = bfbits2f(u.x); t[r][c + 1] = bfbits2f(u.y);
    t[r][c + 2] = bfbits2f(u.z); t[r][c + 3] = bfbits2f(u.w);
  }
  __syncthreads();
#pragma unroll
  for (int i = 0; i < 4; ++i) {
    int idx = i * 1024 + tid * 4;
    int r = idx >> 6, c = idx & 63;  // out row e0+r, cols j0+c..c+3
    alignas(8) bf16 h[4] = {
        __float2bfloat16(t[c][r] * rl[c]), __float2bfloat16(t[c + 1][r] * rl[c + 1]),
        __float2bfloat16(t[c + 2][r] * rl[c + 2]), __float2bfloat16(t[c + 3][r] * rl[c + 3])};
    *(unsigned long long*)(O + (size_t)(e0 + r) * 2048 + j0 + c) = *(const unsigned long long*)h;
  }
}

// ---------------- bt-GEMM: C[m,n] = sum_k A[m,k]*B[n,k], 128x128 tile, BK=64 ----------------
// LDS XOR-swizzle: physical 16B-chunk = logical ^ (row&7); staging permutes the GLOBAL source
// chunk (keeps global_load_lds wave-uniform dest); fragment reads XOR with fm&7 -> 0 conflicts.
// XCD swizzle: lid=(id%8)*(total/8)+id/8 gives each XCD a contiguous logical range (QKV: one
// batch x 3 weights -> A-tile working set 4MB = one L2; P/PV: one batch per XCD).
// EPI: 0 = bf16 store (QKV), 1 = P=exp(acc/32) causal-masked + fused column-sum -> lptr,
//      2 = fp32 store (PV out). VARK: K = (ytile+1)*128, y reversed (long blocks first).
template <int EPI, bool VARK>
__global__ __launch_bounds__(256, 5) void gemm_bt(
    const bf16* __restrict__ A, const bf16* __restrict__ B, void* __restrict__ Cv,
    int lda, int ldb, int ldc, int Kin, int zdivA, int zmodB,
    unsigned long long sA, unsigned long long sB, unsigned long long sC,
    float* __restrict__ lptr) {
  const unsigned gx = gridDim.x, gy = gridDim.y;
  const unsigned total = gx * gy * gridDim.z;
  unsigned id = blockIdx.x + gx * (blockIdx.y + gy * blockIdx.z);
  unsigned lid = (id & 7) * (total >> 3) + (id >> 3);
  const unsigned bx = lid % gx;
  lid /= gx;
  const unsigned by_raw = lid % gy;
  const unsigned bz = lid / gy;
  const unsigned by = VARK ? (gy - 1 - by_raw) : by_raw;  // long-K blocks dispatch first

  if constexpr (EPI == 1) {
    if (bx > by) return;  // strictly-upper score tile: skip
  }
  const int z = (int)bz;
  A += (unsigned long long)(z / zdivA) * sA;
  B += (unsigned long long)(z % zmodB) * sB;
  const int K = VARK ? (int)(by + 1) * 128 : Kin;

  alignas(16) __shared__ bf16 As[128 * 64];
  alignas(16) __shared__ bf16 Bs[128 * 64];

  const int tid = threadIdx.x, wave = tid >> 6, lane = tid & 63;
  const int m0 = by * 128, n0 = bx * 128;
  const int srow = tid >> 3;                        // staging row (per 32-row group)
  const int scol_g = ((tid & 7) ^ (srow & 7)) * 8;  // swizzled GLOBAL chunk
  const int scol_l = (tid & 7) * 8;                 // physical LDS chunk
  const int wm = (wave >> 1) * 64, wn = (wave & 1) * 64;
  const int fm = lane & 15, sw = lane & 7, kg = lane >> 4;

  f32x4 acc[4][4];
#pragma unroll
  for (int mi = 0; mi < 4; ++mi)
#pragma unroll
    for (int ni = 0; ni < 4; ++ni) acc[mi][ni] = (f32x4){0.f, 0.f, 0.f, 0.f};

  const bf16* Arow = A + (size_t)m0 * lda;
  const bf16* Brow = B + (size_t)n0 * ldb;

  for (int k0 = 0; k0 < K; k0 += 64) {
    __syncthreads();  // previous iteration's LDS reads done
#pragma unroll
    for (int c = 0; c < 4; ++c) {
      int row = c * 32 + srow;
      __builtin_amdgcn_global_load_lds(
          (const __attribute__((address_space(1))) void*)(Arow + (size_t)row * lda + k0 + scol_g),
          (__attribute__((address_space(3))) void*)(As + row * 64 + scol_l), 16, 0, 0);
    }
#pragma unroll
    for (int c = 0; c < 4; ++c) {
      int row = c * 32 + srow;
      __builtin_amdgcn_global_load_lds(
          (const __attribute__((address_space(1))) void*)(Brow + (size_t)row * ldb + k0 + scol_g),
          (__attribute__((address_space(3))) void*)(Bs + row * 64 + scol_l), 16, 0, 0);
    }
    __syncthreads();  // drains vmcnt -> staging visible
#pragma unroll
    for (int ks = 0; ks < 2; ++ks) {
      const int pc = ((ks * 4 + kg) ^ sw) * 8;  // swizzled chunk for this lane's rows
      short8 af[4], bf_[4];
#pragma unroll
      for (int i = 0; i < 4; ++i) {
        af[i] = *(const short8*)(As + (wm + i * 16 + fm) * 64 + pc);
        bf_[i] = *(const short8*)(Bs + (wn + i * 16 + fm) * 64 + pc);
      }
#pragma unroll
      for (int mi = 0; mi < 4; ++mi)
#pragma unroll
        for (int ni = 0; ni < 4; ++ni)
          acc[mi][ni] = __builtin_amdgcn_mfma_f32_16x16x32_bf16(af[mi], bf_[ni], acc[mi][ni], 0, 0, 0);
    }
  }

  // epilogue — C/D layout: col = lane&15, row = (lane>>4)*4 + reg
  const int cr = kg * 4, cc = fm;
  if constexpr (EPI == 2) {
    float* C = (float*)Cv + (unsigned long long)z * sC;
#pragma unroll
    for (int mi = 0; mi < 4; ++mi)
#pragma unroll
      for (int ni = 0; ni < 4; ++ni)
#pragma unroll
        for (int r = 0; r < 4; ++r)
          C[(size_t)(m0 + wm + mi * 16 + cr + r) * ldc + (n0 + wn + ni * 16 + cc)] = acc[mi][ni][r];
  } else if constexpr (EPI == 0) {
    bf16* C = (bf16*)Cv + (unsigned long long)z * sC;
#pragma unroll
    for (int mi = 0; mi < 4; ++mi)
#pragma unroll
      for (int ni = 0; ni < 4; ++ni)
#pragma unroll
        for (int r = 0; r < 4; ++r)
          C[(size_t)(m0 + wm + mi * 16 + cr + r) * ldc + (n0 + wn + ni * 16 + cc)] =
              __float2bfloat16(acc[mi][ni][r]);
  } else {
    // EPI == 1: P = exp(acc/32) causal-masked, plus fused column sums into lptr
    bf16* C = (bf16*)Cv + (unsigned long long)z * sC;
    float colpart[4] = {0.f, 0.f, 0.f, 0.f};
#pragma unroll
    for (int mi = 0; mi < 4; ++mi)
#pragma unroll
      for (int ni = 0; ni < 4; ++ni)
#pragma unroll
        for (int r = 0; r < 4; ++r) {
          int gm = m0 + wm + mi * 16 + cr + r;
          int gn = n0 + wn + ni * 16 + cc;
          float s = acc[mi][ni][r] * 0.03125f;     // 1/sqrt(1024)
          float p = (gn <= gm) ? __expf(s) : 0.f;  // causal: j<=i, else exact 0
          colpart[ni] += p;
          C[(size_t)gm * ldc + gn] = __float2bfloat16(p);
        }
    // reduce the 4 row-groups of the wave (lane bits 4,5), then 1 atomic/column
    float* lcol = lptr + (size_t)z * 2048 + n0 + wn;
#pragma unroll
    for (int ni = 0; ni < 4; ++ni) {
      float s = colpart[ni];
      s += __shfl_xor(s, 16);
      s += __shfl_xor(s, 32);
      if (lane < 16) atomicAdd(&lcol[ni * 16 + lane], s);
    }
  }
}

// ---------------- host ----------------
extern "C" void kernel_launch(void* const* d_in, const int* in_sizes, int n_in,
                              void* d_out, int out_size, void* d_ws, size_t ws_size,
                              hipStream_t stream) {
  const float* x = (const float*)d_in[0];
  const float* Wq = (const float*)d_in[1];
  const float* Wk = (const float*)d_in[2];
  const float* Wv = (const float*)d_in[3];
  float* out = (float*)d_out;

  constexpr unsigned long long X_EL = 2048ull * 1024;  // per batch
  constexpr unsigned long long QKV_EL = 3ull * X_EL;
  constexpr unsigned long long P_EL = 2048ull * 2048;
  constexpr unsigned long long VT_EL = 1024ull * 2048;
  constexpr unsigned long long WT_B = 3ull * 1024 * 1024 * 2;
  constexpr unsigned long long LB_B = 8ull * 2048 * 4;  // column sums, all 8 batches
  constexpr unsigned long long PER_B = 2 * (X_EL + QKV_EL + P_EL + VT_EL);

  size_t NB = 1;
  for (size_t nb : {(size_t)8, (size_t)4, (size_t)2})
    if (WT_B + LB_B + nb * PER_B <= ws_size) { NB = nb; break; }

  char* p = (char*)d_ws;
  bf16* Wt = (bf16*)p;   p += WT_B;
  float* lbuf = (float*)p; p += LB_B;
  bf16* Xb = (bf16*)p;   p += 2 * NB * X_EL;
  bf16* QKV = (bf16*)p;  p += 2 * NB * QKV_EL;
  bf16* P = (bf16*)p;    p += 2 * NB * P_EL;
  bf16* Vt = (bf16*)p;

  // weight transpose + zero lbuf (z==3 slice)
  wt_kernel<<<dim3(16, 16, 4), 256, 0, stream>>>(Wq, Wk, Wv, Wt, lbuf);

  for (size_t b0 = 0; b0 < 8; b0 += NB) {
    // x chunk -> bf16
    cvt_kernel<<<dim3((unsigned)(NB * 2048)), 256, 0, stream>>>(x + b0 * X_EL, Xb);
    // Q,K,V = X @ W  (z = lb*3 + weight)
    gemm_bt<0, false><<<dim3(8, 16, (unsigned)(NB * 3)), 256, 0, stream>>>(
        Xb, Wt, QKV, 1024, 1024, 1024, 1024, 3, 3, X_EL, 1048576ull, X_EL, nullptr);
    // P = exp(QK^T/32) lower-triangle tiles, causal-masked, fused column sums
    gemm_bt<1, false><<<dim3(16, 16, (unsigned)NB), 256, 0, stream>>>(
        QKV, QKV + X_EL, P, 1024, 1024, 2048, 1024, 1, 1 << 30, QKV_EL, QKV_EL, P_EL,
        lbuf + b0 * 2048);
    vhat_kernel<<<dim3(32, 16, (unsigned)NB), 256, 0, stream>>>(QKV, lbuf + b0 * 2048, Vt);
    // out = P @ Vt^T, K stops at diagonal tile
    gemm_bt<2, true><<<dim3(8, 16, (unsigned)NB), 256, 0, stream>>>(
        P, Vt, out + b0 * X_EL, 2048, 2048, 1024, 0, 1, 1 << 30, P_EL, VT_EL, X_EL, nullptr);
  }
}

// Round 4
// 340.771 us; speedup vs baseline: 2.2855x; 2.2855x over previous
//
#include <hip/hip_runtime.h>
#include <hip/hip_bf16.h>

// CausalAttention: q=xWq,k=xWk,v=xWv; S=qk^T; causal mask (j>i -> -inf);
// softmax over AXIS=1 (query axis, i.e. COLUMN-wise over i) of S/32; out = W @ v.
// Strategy: P[i,j]=exp(s_ij/32) (no max-sub needed: |s/32|<~2.5), l_j=sum_{i>=j} P
// (fused into P-GEMM epilogue), fold 1/l_j into V rows -> out = P @ (V/l)^T.
// bf16 MFMA GEMMs, XOR-swizzled LDS (0 bank conflicts), XCD-aware block swizzle.
// NOTE: __launch_bounds__ MUST be (256,4): acc needs 64 AGPR + 64 VGPR = 128/wave
// (unified file, ~512/SIMD-slot) -> 4 waves/SIMD exactly. (256,5) forces accumulator
// spill-to-scratch: measured 448MB WRITE_SIZE/dispatch, 3x regression (round 3).

using bf16 = __hip_bfloat16;
typedef __attribute__((ext_vector_type(8))) short short8;
typedef __attribute__((ext_vector_type(4))) float f32x4;

__device__ __forceinline__ float bfbits2f(unsigned short u) {
  return __uint_as_float((unsigned)u << 16);
}

// ---------------- fp32 -> bf16 convert (x4 per thread) ----------------
__global__ void cvt_kernel(const float* __restrict__ in, bf16* __restrict__ out) {
  size_t i = ((size_t)blockIdx.x * 256 + threadIdx.x) * 4;
  float4 v = *(const float4*)(in + i);
  alignas(8) bf16 h[4] = {__float2bfloat16(v.x), __float2bfloat16(v.y),
                          __float2bfloat16(v.z), __float2bfloat16(v.w)};
  *(unsigned long long*)(out + i) = *(const unsigned long long*)h;
}

// ------- W[k][n] fp32 -> Wt[n][k] bf16 (64x64 LDS transpose, vectorized) -------
// z==3 slice: zero the 8*2048 column-sum buffer (folded launch).
__global__ void wt_kernel(const float* __restrict__ W0, const float* __restrict__ W1,
                          const float* __restrict__ W2, bf16* __restrict__ Wt,
                          float* __restrict__ lbuf) {
  int tid = threadIdx.x;
  if (blockIdx.z == 3) {
    int bid = blockIdx.y * 16 + blockIdx.x;
    if (bid < 64) lbuf[bid * 256 + tid] = 0.f;
    return;
  }
  const float* W = blockIdx.z == 0 ? W0 : blockIdx.z == 1 ? W1 : W2;
  bf16* O = Wt + (size_t)blockIdx.z * 1048576ull;
  __shared__ float t[64][65];
  int n0 = blockIdx.x * 64, k0 = blockIdx.y * 64;
#pragma unroll
  for (int i = 0; i < 4; ++i) {
    int idx = i * 1024 + tid * 4;
    int r = idx >> 6, c = idx & 63;
    float4 v = *(const float4*)(W + (size_t)(k0 + r) * 1024 + n0 + c);
    t[r][c] = v.x; t[r][c + 1] = v.y; t[r][c + 2] = v.z; t[r][c + 3] = v.w;
  }
  __syncthreads();
#pragma unroll
  for (int i = 0; i < 4; ++i) {
    int idx = i * 1024 + tid * 4;
    int r = idx >> 6, c = idx & 63;  // out row n0+r, k cols k0+c..c+3
    alignas(8) bf16 h[4] = {__float2bfloat16(t[c][r]), __float2bfloat16(t[c + 1][r]),
                            __float2bfloat16(t[c + 2][r]), __float2bfloat16(t[c + 3][r])};
    *(unsigned long long*)(O + (size_t)(n0 + r) * 1024 + k0 + c) = *(const unsigned long long*)h;
  }
}

// ------- Vt[e][j] = bf16( V[j][e] / l_j )  (64x64 LDS transpose, vectorized) -------
__global__ void vhat_kernel(const bf16* __restrict__ QKV, const float* __restrict__ l,
                            bf16* __restrict__ Vt) {
  int lb = blockIdx.z;
  const unsigned short* V =
      (const unsigned short*)QKV + ((size_t)lb * 3 + 2) * 2097152ull;  // V slot
  bf16* O = Vt + (size_t)lb * 2097152ull;
  const float* lc = l + lb * 2048;
  __shared__ float t[64][65];
  __shared__ float rl[64];
  int j0 = blockIdx.x * 64, e0 = blockIdx.y * 64;
  int tid = threadIdx.x;
  if (tid < 64) rl[tid] = 1.0f / lc[j0 + tid];
#pragma unroll
  for (int i = 0; i < 4; ++i) {
    int idx = i * 1024 + tid * 4;
    int r = idx >> 6, c = idx & 63;
    ushort4 u = *(const ushort4*)(V + (size_t)(j0 + r) * 1024 + e0 + c);
    t[r][c] = bfbits2f(u.x); t[r][c + 1] = bfbits2f(u.y);
    t[r][c + 2] = bfbits2f(u.z); t[r][c + 3] = bfbits2f(u.w);
  }
  __syncthreads();
#pragma unroll
  for (int i = 0; i < 4; ++i) {
    int idx = i * 1024 + tid * 4;
    int r = idx >> 6, c = idx & 63;  // out row e0+r, cols j0+c..c+3
    alignas(8) bf16 h[4] = {
        __float2bfloat16(t[c][r] * rl[c]), __float2bfloat16(t[c + 1][r] * rl[c + 1]),
        __float2bfloat16(t[c + 2][r] * rl[c + 2]), __float2bfloat16(t[c + 3][r] * rl[c + 3])};
    *(unsigned long long*)(O + (size_t)(e0 + r) * 2048 + j0 + c) = *(const unsigned long long*)h;
  }
}

// ---------------- bt-GEMM: C[m,n] = sum_k A[m,k]*B[n,k], 128x128 tile, BK=64 ----------------
// LDS XOR-swizzle: physical 16B-chunk = logical ^ (row&7); staging permutes the GLOBAL source
// chunk (keeps global_load_lds wave-uniform dest); fragment reads XOR with fm&7 -> 0 conflicts.
// XCD swizzle: lid=(id%8)*(total/8)+id/8 gives each XCD a contiguous logical range (QKV: one
// batch x 3 weights -> A-tile working set 4MB = one L2; P/PV: one batch per XCD).
// EPI: 0 = bf16 store (QKV), 1 = P=exp(acc/32) causal-masked + fused column-sum -> lptr,
//      2 = fp32 store (PV out). VARK: K = (ytile+1)*128, y reversed (long blocks first).
template <int EPI, bool VARK>
__global__ __launch_bounds__(256, 4) void gemm_bt(
    const bf16* __restrict__ A, const bf16* __restrict__ B, void* __restrict__ Cv,
    int lda, int ldb, int ldc, int Kin, int zdivA, int zmodB,
    unsigned long long sA, unsigned long long sB, unsigned long long sC,
    float* __restrict__ lptr) {
  const unsigned gx = gridDim.x, gy = gridDim.y;
  const unsigned total = gx * gy * gridDim.z;
  unsigned id = blockIdx.x + gx * (blockIdx.y + gy * blockIdx.z);
  unsigned lid = (id & 7) * (total >> 3) + (id >> 3);
  const unsigned bx = lid % gx;
  lid /= gx;
  const unsigned by_raw = lid % gy;
  const unsigned bz = lid / gy;
  const unsigned by = VARK ? (gy - 1 - by_raw) : by_raw;  // long-K blocks dispatch first

  if constexpr (EPI == 1) {
    if (bx > by) return;  // strictly-upper score tile: skip
  }
  const int z = (int)bz;
  A += (unsigned long long)(z / zdivA) * sA;
  B += (unsigned long long)(z % zmodB) * sB;
  const int K = VARK ? (int)(by + 1) * 128 : Kin;

  alignas(16) __shared__ bf16 As[128 * 64];
  alignas(16) __shared__ bf16 Bs[128 * 64];

  const int tid = threadIdx.x, wave = tid >> 6, lane = tid & 63;
  const int m0 = by * 128, n0 = bx * 128;
  const int srow = tid >> 3;                        // staging row (per 32-row group)
  const int scol_g = ((tid & 7) ^ (srow & 7)) * 8;  // swizzled GLOBAL chunk
  const int scol_l = (tid & 7) * 8;                 // physical LDS chunk
  const int wm = (wave >> 1) * 64, wn = (wave & 1) * 64;
  const int fm = lane & 15, sw = lane & 7, kg = lane >> 4;

  f32x4 acc[4][4];
#pragma unroll
  for (int mi = 0; mi < 4; ++mi)
#pragma unroll
    for (int ni = 0; ni < 4; ++ni) acc[mi][ni] = (f32x4){0.f, 0.f, 0.f, 0.f};

  const bf16* Arow = A + (size_t)m0 * lda;
  const bf16* Brow = B + (size_t)n0 * ldb;

  for (int k0 = 0; k0 < K; k0 += 64) {
    __syncthreads();  // previous iteration's LDS reads done
#pragma unroll
    for (int c = 0; c < 4; ++c) {
      int row = c * 32 + srow;
      __builtin_amdgcn_global_load_lds(
          (const __attribute__((address_space(1))) void*)(Arow + (size_t)row * lda + k0 + scol_g),
          (__attribute__((address_space(3))) void*)(As + row * 64 + scol_l), 16, 0, 0);
    }
#pragma unroll
    for (int c = 0; c < 4; ++c) {
      int row = c * 32 + srow;
      __builtin_amdgcn_global_load_lds(
          (const __attribute__((address_space(1))) void*)(Brow + (size_t)row * ldb + k0 + scol_g),
          (__attribute__((address_space(3))) void*)(Bs + row * 64 + scol_l), 16, 0, 0);
    }
    __syncthreads();  // drains vmcnt -> staging visible
#pragma unroll
    for (int ks = 0; ks < 2; ++ks) {
      const int pc = ((ks * 4 + kg) ^ sw) * 8;  // swizzled chunk for this lane's rows
      short8 af[4], bf_[4];
#pragma unroll
      for (int i = 0; i < 4; ++i) {
        af[i] = *(const short8*)(As + (wm + i * 16 + fm) * 64 + pc);
        bf_[i] = *(const short8*)(Bs + (wn + i * 16 + fm) * 64 + pc);
      }
#pragma unroll
      for (int mi = 0; mi < 4; ++mi)
#pragma unroll
        for (int ni = 0; ni < 4; ++ni)
          acc[mi][ni] = __builtin_amdgcn_mfma_f32_16x16x32_bf16(af[mi], bf_[ni], acc[mi][ni], 0, 0, 0);
    }
  }

  // epilogue — C/D layout: col = lane&15, row = (lane>>4)*4 + reg
  const int cr = kg * 4, cc = fm;
  if constexpr (EPI == 2) {
    float* C = (float*)Cv + (unsigned long long)z * sC;
#pragma unroll
    for (int mi = 0; mi < 4; ++mi)
#pragma unroll
      for (int ni = 0; ni < 4; ++ni)
#pragma unroll
        for (int r = 0; r < 4; ++r)
          C[(size_t)(m0 + wm + mi * 16 + cr + r) * ldc + (n0 + wn + ni * 16 + cc)] = acc[mi][ni][r];
  } else if constexpr (EPI == 0) {
    bf16* C = (bf16*)Cv + (unsigned long long)z * sC;
#pragma unroll
    for (int mi = 0; mi < 4; ++mi)
#pragma unroll
      for (int ni = 0; ni < 4; ++ni)
#pragma unroll
        for (int r = 0; r < 4; ++r)
          C[(size_t)(m0 + wm + mi * 16 + cr + r) * ldc + (n0 + wn + ni * 16 + cc)] =
              __float2bfloat16(acc[mi][ni][r]);
  } else {
    // EPI == 1: P = exp(acc/32) causal-masked, plus fused column sums into lptr
    bf16* C = (bf16*)Cv + (unsigned long long)z * sC;
    float colpart[4] = {0.f, 0.f, 0.f, 0.f};
#pragma unroll
    for (int mi = 0; mi < 4; ++mi)
#pragma unroll
      for (int ni = 0; ni < 4; ++ni)
#pragma unroll
        for (int r = 0; r < 4; ++r) {
          int gm = m0 + wm + mi * 16 + cr + r;
          int gn = n0 + wn + ni * 16 + cc;
          float s = acc[mi][ni][r] * 0.03125f;     // 1/sqrt(1024)
          float p = (gn <= gm) ? __expf(s) : 0.f;  // causal: j<=i, else exact 0
          colpart[ni] += p;
          C[(size_t)gm * ldc + gn] = __float2bfloat16(p);
        }
    // reduce the 4 row-groups of the wave (lane bits 4,5), then 1 atomic/column
    float* lcol = lptr + (size_t)z * 2048 + n0 + wn;
#pragma unroll
    for (int ni = 0; ni < 4; ++ni) {
      float s = colpart[ni];
      s += __shfl_xor(s, 16);
      s += __shfl_xor(s, 32);
      if (lane < 16) atomicAdd(&lcol[ni * 16 + lane], s);
    }
  }
}

// ---------------- host ----------------
extern "C" void kernel_launch(void* const* d_in, const int* in_sizes, int n_in,
                              void* d_out, int out_size, void* d_ws, size_t ws_size,
                              hipStream_t stream) {
  const float* x = (const float*)d_in[0];
  const float* Wq = (const float*)d_in[1];
  const float* Wk = (const float*)d_in[2];
  const float* Wv = (const float*)d_in[3];
  float* out = (float*)d_out;

  constexpr unsigned long long X_EL = 2048ull * 1024;  // per batch
  constexpr unsigned long long QKV_EL = 3ull * X_EL;
  constexpr unsigned long long P_EL = 2048ull * 2048;
  constexpr unsigned long long VT_EL = 1024ull * 2048;
  constexpr unsigned long long WT_B = 3ull * 1024 * 1024 * 2;
  constexpr unsigned long long LB_B = 8ull * 2048 * 4;  // column sums, all 8 batches
  constexpr unsigned long long PER_B = 2 * (X_EL + QKV_EL + P_EL + VT_EL);

  size_t NB = 1;
  for (size_t nb : {(size_t)8, (size_t)4, (size_t)2})
    if (WT_B + LB_B + nb * PER_B <= ws_size) { NB = nb; break; }

  char* p = (char*)d_ws;
  bf16* Wt = (bf16*)p;   p += WT_B;
  float* lbuf = (float*)p; p += LB_B;
  bf16* Xb = (bf16*)p;   p += 2 * NB * X_EL;
  bf16* QKV = (bf16*)p;  p += 2 * NB * QKV_EL;
  bf16* P = (bf16*)p;    p += 2 * NB * P_EL;
  bf16* Vt = (bf16*)p;

  // weight transpose + zero lbuf (z==3 slice)
  wt_kernel<<<dim3(16, 16, 4), 256, 0, stream>>>(Wq, Wk, Wv, Wt, lbuf);

  for (size_t b0 = 0; b0 < 8; b0 += NB) {
    // x chunk -> bf16
    cvt_kernel<<<dim3((unsigned)(NB * 2048)), 256, 0, stream>>>(x + b0 * X_EL, Xb);
    // Q,K,V = X @ W  (z = lb*3 + weight)
    gemm_bt<0, false><<<dim3(8, 16, (unsigned)(NB * 3)), 256, 0, stream>>>(
        Xb, Wt, QKV, 1024, 1024, 1024, 1024, 3, 3, X_EL, 1048576ull, X_EL, nullptr);
    // P = exp(QK^T/32) lower-triangle tiles, causal-masked, fused column sums
    gemm_bt<1, false><<<dim3(16, 16, (unsigned)NB), 256, 0, stream>>>(
        QKV, QKV + X_EL, P, 1024, 1024, 2048, 1024, 1, 1 << 30, QKV_EL, QKV_EL, P_EL,
        lbuf + b0 * 2048);
    vhat_kernel<<<dim3(32, 16, (unsigned)NB), 256, 0, stream>>>(QKV, lbuf + b0 * 2048, Vt);
    // out = P @ Vt^T, K stops at diagonal tile
    gemm_bt<2, true><<<dim3(8, 16, (unsigned)NB), 256, 0, stream>>>(
        P, Vt, out + b0 * X_EL, 2048, 2048, 1024, 0, 1, 1 << 30, P_EL, VT_EL, X_EL, nullptr);
  }
}

// Round 5
// 339.183 us; speedup vs baseline: 2.2962x; 1.0047x over previous
//
#include <hip/hip_runtime.h>
#include <hip/hip_bf16.h>

// CausalAttention: q=xWq,k=xWk,v=xWv; S=qk^T; causal mask (j>i -> -inf);
// softmax over AXIS=1 (query axis, i.e. COLUMN-wise over i) of S/32; out = W @ v.
// Strategy: P[i,j]=exp(s_ij/32) (no max-sub needed: |s/32|<~2.5), l_j=sum_{i>=j} P
// (fused into P-GEMM epilogue), fold 1/l_j into V rows -> out = P @ (V/l)^T.
// bf16 MFMA GEMMs, XOR-swizzled LDS (0 bank conflicts), XCD-aware block swizzle
// (R4: QKV FETCH hit the 80MB analytic floor) + banded traversal within XCD
// (R5: B-tile read once per band, A-band L2-resident -> kills P/PV L2 thrash).
// NOTE: __launch_bounds__ MUST be (256,4): acc needs 64 AGPR + 64 VGPR = 128/wave
// (unified file, ~512/SIMD-slot). (256,5) spills accumulators: 448MB WRITE, 3x slower (R3).

using bf16 = __hip_bfloat16;
typedef __attribute__((ext_vector_type(8))) short short8;
typedef __attribute__((ext_vector_type(4))) float f32x4;

__device__ __forceinline__ float bfbits2f(unsigned short u) {
  return __uint_as_float((unsigned)u << 16);
}

// ---------------- fp32 -> bf16 convert (x4 per thread) ----------------
__global__ void cvt_kernel(const float* __restrict__ in, bf16* __restrict__ out) {
  size_t i = ((size_t)blockIdx.x * 256 + threadIdx.x) * 4;
  float4 v = *(const float4*)(in + i);
  alignas(8) bf16 h[4] = {__float2bfloat16(v.x), __float2bfloat16(v.y),
                          __float2bfloat16(v.z), __float2bfloat16(v.w)};
  *(unsigned long long*)(out + i) = *(const unsigned long long*)h;
}

// ------- W[k][n] fp32 -> Wt[n][k] bf16 (64x64 LDS transpose, vectorized) -------
// z==3 slice: zero the 8*2048 column-sum buffer (folded launch).
__global__ void wt_kernel(const float* __restrict__ W0, const float* __restrict__ W1,
                          const float* __restrict__ W2, bf16* __restrict__ Wt,
                          float* __restrict__ lbuf) {
  int tid = threadIdx.x;
  if (blockIdx.z == 3) {
    int bid = blockIdx.y * 16 + blockIdx.x;
    if (bid < 64) lbuf[bid * 256 + tid] = 0.f;
    return;
  }
  const float* W = blockIdx.z == 0 ? W0 : blockIdx.z == 1 ? W1 : W2;
  bf16* O = Wt + (size_t)blockIdx.z * 1048576ull;
  __shared__ float t[64][65];
  int n0 = blockIdx.x * 64, k0 = blockIdx.y * 64;
#pragma unroll
  for (int i = 0; i < 4; ++i) {
    int idx = i * 1024 + tid * 4;
    int r = idx >> 6, c = idx & 63;
    float4 v = *(const float4*)(W + (size_t)(k0 + r) * 1024 + n0 + c);
    t[r][c] = v.x; t[r][c + 1] = v.y; t[r][c + 2] = v.z; t[r][c + 3] = v.w;
  }
  __syncthreads();
#pragma unroll
  for (int i = 0; i < 4; ++i) {
    int idx = i * 1024 + tid * 4;
    int r = idx >> 6, c = idx & 63;  // out row n0+r, k cols k0+c..c+3
    alignas(8) bf16 h[4] = {__float2bfloat16(t[c][r]), __float2bfloat16(t[c + 1][r]),
                            __float2bfloat16(t[c + 2][r]), __float2bfloat16(t[c + 3][r])};
    *(unsigned long long*)(O + (size_t)(n0 + r) * 1024 + k0 + c) = *(const unsigned long long*)h;
  }
}

// ------- Vt[e][j] = bf16( V[j][e] / l_j )  (64x64 LDS transpose, vectorized) -------
__global__ void vhat_kernel(const bf16* __restrict__ QKV, const float* __restrict__ l,
                            bf16* __restrict__ Vt) {
  int lb = blockIdx.z;
  const unsigned short* V =
      (const unsigned short*)QKV + ((size_t)lb * 3 + 2) * 2097152ull;  // V slot
  bf16* O = Vt + (size_t)lb * 2097152ull;
  const float* lc = l + lb * 2048;
  __shared__ float t[64][65];
  __shared__ float rl[64];
  int j0 = blockIdx.x * 64, e0 = blockIdx.y * 64;
  int tid = threadIdx.x;
  if (tid < 64) rl[tid] = 1.0f / lc[j0 + tid];
#pragma unroll
  for (int i = 0; i < 4; ++i) {
    int idx = i * 1024 + tid * 4;
    int r = idx >> 6, c = idx & 63;
    ushort4 u = *(const ushort4*)(V + (size_t)(j0 + r) * 1024 + e0 + c);
    t[r][c] = bfbits2f(u.x); t[r][c + 1] = bfbits2f(u.y);
    t[r][c + 2] = bfbits2f(u.z); t[r][c + 3] = bfbits2f(u.w);
  }
  __syncthreads();
#pragma unroll
  for (int i = 0; i < 4; ++i) {
    int idx = i * 1024 + tid * 4;
    int r = idx >> 6, c = idx & 63;  // out row e0+r, cols j0+c..c+3
    alignas(8) bf16 h[4] = {
        __float2bfloat16(t[c][r] * rl[c]), __float2bfloat16(t[c + 1][r] * rl[c + 1]),
        __float2bfloat16(t[c + 2][r] * rl[c + 2]), __float2bfloat16(t[c + 3][r] * rl[c + 3])};
    *(unsigned long long*)(O + (size_t)(e0 + r) * 2048 + j0 + c) = *(const unsigned long long*)h;
  }
}

// ---------------- bt-GEMM body: C[m,n] = sum_k A[m,k]*B[n,k], 128x128 tile, BK=64 ----------------
// LDS XOR-swizzle: physical 16B-chunk = logical ^ (row&7); staging permutes the GLOBAL source
// chunk (keeps global_load_lds wave-uniform dest); fragment reads XOR with fm&7 -> 0 conflicts.
// Block decode: XCD swizzle (lid=(id%8)*(total/8)+id/8 -> contiguous logical range per XCD)
// then BANDED traversal: bands of H=8 rows, x outer / h inner -> consecutive blocks share one
// B tile (read once per band) while the A band (<=3.2MB) stays resident in the XCD's 4MB L2.
// EPI: 0 = bf16 store (QKV), 1 = P=exp(acc/32) causal-masked + fused column-sum -> lptr,
//      2 = fp32 store (PV out). VARK: K = (by+1)*128, y reversed (long-K blocks first).
template <int EPI, bool VARK>
__device__ __forceinline__ void gemm_bt_body(
    const bf16* __restrict__ A, const bf16* __restrict__ B, void* __restrict__ Cv,
    int lda, int ldb, int ldc, int Kin, int zdivA, int zmodB,
    unsigned long long sA, unsigned long long sB, unsigned long long sC,
    float* __restrict__ lptr) {
  const unsigned gx = gridDim.x, gy = gridDim.y;
  const unsigned per_z = gx * gy;
  const unsigned total = per_z * gridDim.z;
  unsigned id = blockIdx.x + gx * (blockIdx.y + gy * blockIdx.z);
  unsigned lid = (id & 7) * (total >> 3) + (id >> 3);
  const unsigned bz = lid / per_z;
  unsigned rem = lid - bz * per_z;
  constexpr unsigned H = 8;  // band height (gy=16 -> 2 bands per z)
  const unsigned band = rem / (gx * H);
  const unsigned w = rem - band * (gx * H);
  const unsigned bx = w / H;
  const unsigned by_raw = band * H + (w - bx * H);
  const unsigned by = VARK ? (gy - 1 - by_raw) : by_raw;

  if constexpr (EPI == 1) {
    if (bx > by) return;  // strictly-upper score tile: skip
  }
  const int z = (int)bz;
  A += (unsigned long long)(z / zdivA) * sA;
  B += (unsigned long long)(z % zmodB) * sB;
  const int K = VARK ? (int)(by + 1) * 128 : Kin;

  alignas(16) __shared__ bf16 As[128 * 64];
  alignas(16) __shared__ bf16 Bs[128 * 64];

  const int tid = threadIdx.x, wave = tid >> 6, lane = tid & 63;
  const int m0 = by * 128, n0 = bx * 128;
  const int srow = tid >> 3;                        // staging row (per 32-row group)
  const int scol_g = ((tid & 7) ^ (srow & 7)) * 8;  // swizzled GLOBAL chunk
  const int scol_l = (tid & 7) * 8;                 // physical LDS chunk
  const int wm = (wave >> 1) * 64, wn = (wave & 1) * 64;
  const int fm = lane & 15, sw = lane & 7, kg = lane >> 4;

  f32x4 acc[4][4];
#pragma unroll
  for (int mi = 0; mi < 4; ++mi)
#pragma unroll
    for (int ni = 0; ni < 4; ++ni) acc[mi][ni] = (f32x4){0.f, 0.f, 0.f, 0.f};

  const bf16* Arow = A + (size_t)m0 * lda;
  const bf16* Brow = B + (size_t)n0 * ldb;

  for (int k0 = 0; k0 < K; k0 += 64) {
    __syncthreads();  // previous iteration's LDS reads done
#pragma unroll
    for (int c = 0; c < 4; ++c) {
      int row = c * 32 + srow;
      __builtin_amdgcn_global_load_lds(
          (const __attribute__((address_space(1))) void*)(Arow + (size_t)row * lda + k0 + scol_g),
          (__attribute__((address_space(3))) void*)(As + row * 64 + scol_l), 16, 0, 0);
    }
#pragma unroll
    for (int c = 0; c < 4; ++c) {
      int row = c * 32 + srow;
      __builtin_amdgcn_global_load_lds(
          (const __attribute__((address_space(1))) void*)(Brow + (size_t)row * ldb + k0 + scol_g),
          (__attribute__((address_space(3))) void*)(Bs + row * 64 + scol_l), 16, 0, 0);
    }
    __syncthreads();  // drains vmcnt -> staging visible
#pragma unroll
    for (int ks = 0; ks < 2; ++ks) {
      const int pc = ((ks * 4 + kg) ^ sw) * 8;  // swizzled chunk for this lane's rows
      short8 af[4], bf_[4];
#pragma unroll
      for (int i = 0; i < 4; ++i) {
        af[i] = *(const short8*)(As + (wm + i * 16 + fm) * 64 + pc);
        bf_[i] = *(const short8*)(Bs + (wn + i * 16 + fm) * 64 + pc);
      }
#pragma unroll
      for (int mi = 0; mi < 4; ++mi)
#pragma unroll
        for (int ni = 0; ni < 4; ++ni)
          acc[mi][ni] = __builtin_amdgcn_mfma_f32_16x16x32_bf16(af[mi], bf_[ni], acc[mi][ni], 0, 0, 0);
    }
  }

  // epilogue — C/D layout: col = lane&15, row = (lane>>4)*4 + reg
  const int cr = kg * 4, cc = fm;
  if constexpr (EPI == 2) {
    float* C = (float*)Cv + (unsigned long long)z * sC;
#pragma unroll
    for (int mi = 0; mi < 4; ++mi)
#pragma unroll
      for (int ni = 0; ni < 4; ++ni)
#pragma unroll
        for (int r = 0; r < 4; ++r)
          C[(size_t)(m0 + wm + mi * 16 + cr + r) * ldc + (n0 + wn + ni * 16 + cc)] = acc[mi][ni][r];
  } else if constexpr (EPI == 0) {
    bf16* C = (bf16*)Cv + (unsigned long long)z * sC;
#pragma unroll
    for (int mi = 0; mi < 4; ++mi)
#pragma unroll
      for (int ni = 0; ni < 4; ++ni)
#pragma unroll
        for (int r = 0; r < 4; ++r)
          C[(size_t)(m0 + wm + mi * 16 + cr + r) * ldc + (n0 + wn + ni * 16 + cc)] =
              __float2bfloat16(acc[mi][ni][r]);
  } else {
    // EPI == 1: P = exp(acc/32) causal-masked, plus fused column sums into lptr
    bf16* C = (bf16*)Cv + (unsigned long long)z * sC;
    float colpart[4] = {0.f, 0.f, 0.f, 0.f};
#pragma unroll
    for (int mi = 0; mi < 4; ++mi)
#pragma unroll
      for (int ni = 0; ni < 4; ++ni)
#pragma unroll
        for (int r = 0; r < 4; ++r) {
          int gm = m0 + wm + mi * 16 + cr + r;
          int gn = n0 + wn + ni * 16 + cc;
          float s = acc[mi][ni][r] * 0.03125f;     // 1/sqrt(1024)
          float p = (gn <= gm) ? __expf(s) : 0.f;  // causal: j<=i, else exact 0
          colpart[ni] += p;
          C[(size_t)gm * ldc + gn] = __float2bfloat16(p);
        }
    // reduce the 4 row-groups of the wave (lane bits 4,5), then 1 atomic/column
    float* lcol = lptr + (size_t)z * 2048 + n0 + wn;
#pragma unroll
    for (int ni = 0; ni < 4; ++ni) {
      float s = colpart[ni];
      s += __shfl_xor(s, 16);
      s += __shfl_xor(s, 32);
      if (lane < 16) atomicAdd(&lcol[ni * 16 + lane], s);
    }
  }
}

// Distinct kernel names so rocprof's per-dispatch table separates the three GEMMs.
__global__ __launch_bounds__(256, 4) void gemm_qkv(
    const bf16* __restrict__ A, const bf16* __restrict__ B, void* __restrict__ Cv,
    int lda, int ldb, int ldc, int Kin, int zdivA, int zmodB,
    unsigned long long sA, unsigned long long sB, unsigned long long sC) {
  gemm_bt_body<0, false>(A, B, Cv, lda, ldb, ldc, Kin, zdivA, zmodB, sA, sB, sC, nullptr);
}
__global__ __launch_bounds__(256, 4) void gemm_scores(
    const bf16* __restrict__ A, const bf16* __restrict__ B, void* __restrict__ Cv,
    int lda, int ldb, int ldc, int Kin, int zdivA, int zmodB,
    unsigned long long sA, unsigned long long sB, unsigned long long sC,
    float* __restrict__ lptr) {
  gemm_bt_body<1, false>(A, B, Cv, lda, ldb, ldc, Kin, zdivA, zmodB, sA, sB, sC, lptr);
}
__global__ __launch_bounds__(256, 4) void gemm_pv(
    const bf16* __restrict__ A, const bf16* __restrict__ B, void* __restrict__ Cv,
    int lda, int ldb, int ldc, int Kin, int zdivA, int zmodB,
    unsigned long long sA, unsigned long long sB, unsigned long long sC) {
  gemm_bt_body<2, true>(A, B, Cv, lda, ldb, ldc, Kin, zdivA, zmodB, sA, sB, sC, nullptr);
}

// ---------------- host ----------------
extern "C" void kernel_launch(void* const* d_in, const int* in_sizes, int n_in,
                              void* d_out, int out_size, void* d_ws, size_t ws_size,
                              hipStream_t stream) {
  const float* x = (const float*)d_in[0];
  const float* Wq = (const float*)d_in[1];
  const float* Wk = (const float*)d_in[2];
  const float* Wv = (const float*)d_in[3];
  float* out = (float*)d_out;

  constexpr unsigned long long X_EL = 2048ull * 1024;  // per batch
  constexpr unsigned long long QKV_EL = 3ull * X_EL;
  constexpr unsigned long long P_EL = 2048ull * 2048;
  constexpr unsigned long long VT_EL = 1024ull * 2048;
  constexpr unsigned long long WT_B = 3ull * 1024 * 1024 * 2;
  constexpr unsigned long long LB_B = 8ull * 2048 * 4;  // column sums, all 8 batches
  constexpr unsigned long long PER_B = 2 * (X_EL + QKV_EL + P_EL + VT_EL);

  size_t NB = 1;
  for (size_t nb : {(size_t)8, (size_t)4, (size_t)2})
    if (WT_B + LB_B + nb * PER_B <= ws_size) { NB = nb; break; }

  char* p = (char*)d_ws;
  bf16* Wt = (bf16*)p;   p += WT_B;
  float* lbuf = (float*)p; p += LB_B;
  bf16* Xb = (bf16*)p;   p += 2 * NB * X_EL;
  bf16* QKV = (bf16*)p;  p += 2 * NB * QKV_EL;
  bf16* P = (bf16*)p;    p += 2 * NB * P_EL;
  bf16* Vt = (bf16*)p;

  // weight transpose + zero lbuf (z==3 slice)
  wt_kernel<<<dim3(16, 16, 4), 256, 0, stream>>>(Wq, Wk, Wv, Wt, lbuf);

  for (size_t b0 = 0; b0 < 8; b0 += NB) {
    // x chunk -> bf16
    cvt_kernel<<<dim3((unsigned)(NB * 2048)), 256, 0, stream>>>(x + b0 * X_EL, Xb);
    // Q,K,V = X @ W  (z = lb*3 + weight)
    gemm_qkv<<<dim3(8, 16, (unsigned)(NB * 3)), 256, 0, stream>>>(
        Xb, Wt, QKV, 1024, 1024, 1024, 1024, 3, 3, X_EL, 1048576ull, X_EL);
    // P = exp(QK^T/32) lower-triangle tiles, causal-masked, fused column sums
    gemm_scores<<<dim3(16, 16, (unsigned)NB), 256, 0, stream>>>(
        QKV, QKV + X_EL, P, 1024, 1024, 2048, 1024, 1, 1 << 30, QKV_EL, QKV_EL, P_EL,
        lbuf + b0 * 2048);
    vhat_kernel<<<dim3(32, 16, (unsigned)NB), 256, 0, stream>>>(QKV, lbuf + b0 * 2048, Vt);
    // out = P @ Vt^T, K stops at diagonal tile
    gemm_pv<<<dim3(8, 16, (unsigned)NB), 256, 0, stream>>>(
        P, Vt, out + b0 * X_EL, 2048, 2048, 1024, 0, 1, 1 << 30, P_EL, VT_EL, X_EL);
  }
}